// Round 11
// baseline (22.426 us; speedup 1.0000x reference)
//
#include <hip/hip_runtime.h>

// Aggregation (SAN-style): out[n,c,l] = sum_kk input_pad[n,c,tap(l,kk)] * weight[n, c/8, kk, l]
// N=8, C=256, Cw=32, share=8, K=3, H=W=56, L=3136. All fp32.
//
// R11 = R10 structure with 8-row bands (halo overhead 50%->25%, per-wave
// in-flight bytes 2x). Wave = 56 active lanes = 8 rows x 7 octs; each lane
// owns 8 consecutive cols (two float4s) of ONE channel row. Block = 8 waves
// = 8 share-channels of one (n,g,band). Grid = 8*32*7 = 1792 = 7 blocks/CU
// exact; XCD swizzle bijective (1792 = 8*224). Vertical taps via shfl +/-7,
// horizontal edge cols via shfl +/-1, zero-pad via lane masks.

#define HH 56
#define WW 56
#define LL 3136
#define CW 32
#define CC 256
#define NN 8
#define NWG (NN * CW * 7)   // 1792 blocks
#define CHUNK (NWG / 8)     // 224 per XCD

__global__ __launch_bounds__(512) void agg_kernel(const float* __restrict__ in,
                                                  const float* __restrict__ wt,
                                                  float* __restrict__ out) {
    const unsigned t    = threadIdx.x;
    const unsigned wid  = t >> 6;              // 0..7 -> channel within group
    const unsigned lane = t & 63u;
    const unsigned bp   = blockIdx.x;
    const unsigned b    = (bp & 7u) * CHUNK + (bp >> 3);   // XCD swizzle
    const unsigned band = b % 7u;              // 8-row band
    const unsigned ng   = b / 7u;
    const unsigned g    = ng & 31u;
    const unsigned n    = ng >> 5;

    const unsigned rq = (lane < 56u) ? lane : 55u;  // clamp tail lanes
    const unsigned r  = rq / 7u;               // row in band, 0..7
    const unsigned q  = rq - r * 7u;           // oct in row, 0..6
    const unsigned h  = band * 8u + r;         // global row 0..55
    const unsigned w8 = q * 8u;
    const unsigned l  = h * WW + w8;           // 16B-aligned

    const unsigned c  = g * 8u + wid;
    const float* ip = in + ((size_t)n * CC + c) * LL;

    // ---- center row (8 floats) + masked band-halo rows ----
    const float4 cA = *(const float4*)(ip + l);
    const float4 cB = *(const float4*)(ip + l + 4);
    float4 hmA = make_float4(0.f,0.f,0.f,0.f), hmB = hmA;
    float4 hpA = hmA, hpB = hmA;
    if (r == 0u && h > 0u)      { hmA = *(const float4*)(ip + l - WW);
                                  hmB = *(const float4*)(ip + l - WW + 4); }
    if (r == 7u && h < HH - 1u) { hpA = *(const float4*)(ip + l + WW);
                                  hpB = *(const float4*)(ip + l + WW + 4); }

    float cv[8] = {cA.x, cA.y, cA.z, cA.w, cB.x, cB.y, cB.z, cB.w};
    float hm[8] = {hmA.x, hmA.y, hmA.z, hmA.w, hmB.x, hmB.y, hmB.z, hmB.w};
    float hp[8] = {hpA.x, hpA.y, hpA.z, hpA.w, hpB.x, hpB.y, hpB.z, hpB.w};

    // ---- vertical rows h-1 / h+1: neighbor lanes (+-7) or halo ----
    float cm[8], cp[8];
#pragma unroll
    for (int i = 0; i < 8; ++i) {
        const float su = __shfl_up(cv[i], 7);
        const float sd = __shfl_down(cv[i], 7);
        cm[i] = (r == 0u) ? hm[i] : su;
        cp[i] = (r == 7u) ? hp[i] : sd;
    }

    // ---- horizontal edge cols (8q-1 and 8q+8) via shfl +-1 ----
    float lm = __shfl_up(cm[7], 1), lc = __shfl_up(cv[7], 1), lp = __shfl_up(cp[7], 1);
    float em = __shfl_down(cm[0], 1), ec = __shfl_down(cv[0], 1), ep = __shfl_down(cp[0], 1);
    if (q == 0u) { lm = 0.f; lc = 0.f; lp = 0.f; }
    if (q == 6u) { em = 0.f; ec = 0.f; ep = 0.f; }

    // ---- 10-wide windows per row: [col-1, col0..7, col+8] ----
    float win[3][10];
#pragma unroll
    for (int i = 0; i < 8; ++i) { win[0][i+1] = cm[i]; win[1][i+1] = cv[i]; win[2][i+1] = cp[i]; }
    win[0][0] = lm; win[1][0] = lc; win[2][0] = lp;
    win[0][9] = em; win[1][9] = ec; win[2][9] = ep;

    // ---- taps: 9 weight oct-loads, 72 FMA ----
    const float* wp = wt + (((size_t)n * CW + g) * 9u) * LL + l;
    float acc[8] = {0.f, 0.f, 0.f, 0.f, 0.f, 0.f, 0.f, 0.f};
#pragma unroll
    for (int dr = 0; dr < 3; ++dr) {
#pragma unroll
        for (int dw = 0; dw < 3; ++dw) {
            const int k = dr * 3 + dw;
            const float4 wA = *(const float4*)(wp + (size_t)k * LL);
            const float4 wB = *(const float4*)(wp + (size_t)k * LL + 4);
            const float wv8[8] = {wA.x, wA.y, wA.z, wA.w, wB.x, wB.y, wB.z, wB.w};
#pragma unroll
            for (int e = 0; e < 8; ++e)
                acc[e] = fmaf(win[dr][e + dw], wv8[e], acc[e]);
        }
    }

    if (lane < 56u) {
        float* op = out + ((size_t)n * CC + c) * LL + l;
        *(float4*)op       = make_float4(acc[0], acc[1], acc[2], acc[3]);
        *(float4*)(op + 4) = make_float4(acc[4], acc[5], acc[6], acc[7]);
    }
}

extern "C" void kernel_launch(void* const* d_in, const int* in_sizes, int n_in,
                              void* d_out, int out_size, void* d_ws, size_t ws_size,
                              hipStream_t stream) {
    const float* in = (const float*)d_in[0];
    const float* wt = (const float*)d_in[1];
    float* out = (float*)d_out;
    agg_kernel<<<dim3(NWG), dim3(512), 0, stream>>>(in, wt, out);
}

// Round 12
// 18.952 us; speedup vs baseline: 1.1833x; 1.1833x over previous
//
#include <hip/hip_runtime.h>

// Aggregation (SAN-style): out[n,c,l] = sum_kk input_pad[n,c,tap(l,kk)] * weight[n, c/8, kk, l]
// N=8, C=256, Cw=32, share=8, K=3, H=W=56, L=3136. All fp32.
//
// FINAL (= R10, session best 19.03 us): wave = 56 active lanes = 4 rows x
// 14 quads of ONE channel; block = 8 waves = the 8 share-channels of one
// (n, g, 4-row band). Weight float4s block-shared -> L1 reuse. Vertical taps
// via shfl +/-14, horizontal edges via shfl +/-1, zero-pad via lane masks.
// XCD-aware bijective block swizzle (3584 = 8*448) keeps all bands of each
// (n,g) on one XCD so halo/weight re-reads hit that XCD's L2 (-6% measured).

#define HH 56
#define WW 56
#define LL 3136
#define CW 32
#define CC 256
#define NN 8
#define NWG (NN * CW * 14)   // 3584 blocks
#define CHUNK (NWG / 8)      // 448 per XCD

__device__ __forceinline__ float4 shfl_up4(float4 v, int d) {
    return make_float4(__shfl_up(v.x, d), __shfl_up(v.y, d),
                       __shfl_up(v.z, d), __shfl_up(v.w, d));
}
__device__ __forceinline__ float4 shfl_down4(float4 v, int d) {
    return make_float4(__shfl_down(v.x, d), __shfl_down(v.y, d),
                       __shfl_down(v.z, d), __shfl_down(v.w, d));
}

__global__ __launch_bounds__(512) void agg_kernel(const float* __restrict__ in,
                                                  const float* __restrict__ wt,
                                                  float* __restrict__ out) {
    const unsigned t    = threadIdx.x;
    const unsigned wid  = t >> 6;              // 0..7 -> channel within group
    const unsigned lane = t & 63u;
    // XCD swizzle: physical blocks round-robin XCDs; make work-ids contiguous per XCD.
    const unsigned bp   = blockIdx.x;
    const unsigned b    = (bp & 7u) * CHUNK + (bp >> 3);
    const unsigned band = b % 14u;             // 4-row band
    const unsigned ng   = b / 14u;
    const unsigned g    = ng & 31u;
    const unsigned n    = ng >> 5;

    const unsigned rq = (lane < 56u) ? lane : 55u;  // clamp tail lanes
    const unsigned r  = rq / 14u;              // row in band, 0..3
    const unsigned q  = rq - r * 14u;          // quad in row, 0..13
    const unsigned h  = band * 4u + r;         // global row 0..55
    const unsigned w4 = q * 4u;
    const unsigned l  = h * WW + w4;           // 16B-aligned

    // ---- 9 weight float4 loads (block-shared addresses -> L1 reuse) ----
    const float* wp = wt + (((size_t)n * CW + g) * 9u) * LL + l;
    float4 wv[9];
#pragma unroll
    for (int k = 0; k < 9; ++k) wv[k] = *(const float4*)(wp + (size_t)k * LL);

    // ---- input: own center row + masked band-halo rows ----
    const unsigned c = g * 8u + wid;
    const float* ip = in + ((size_t)n * CC + c) * LL;
    const float4 c4 = *(const float4*)(ip + l);
    float4 hm = make_float4(0.f, 0.f, 0.f, 0.f);
    float4 hp = make_float4(0.f, 0.f, 0.f, 0.f);
    if (r == 0u && h > 0u)       hm = *(const float4*)(ip + l - WW);
    if (r == 3u && h < HH - 1u)  hp = *(const float4*)(ip + l + WW);

    // ---- vertical windows: row h-1 / h+1 from neighbor lanes or halo ----
    const float4 sm = shfl_up4(c4, 14);
    const float4 sp = shfl_down4(c4, 14);
    const float4 rm = (r == 0u) ? hm : sm;
    const float4 rp = (r == 3u) ? hp : sp;

    // ---- horizontal edges: prev quad's .w / next quad's .x ----
    const bool qz = (q == 0u), qe = (q == 13u);
    float lm = __shfl_up(rm.w, 1), lc = __shfl_up(c4.w, 1), lp = __shfl_up(rp.w, 1);
    float em = __shfl_down(rm.x, 1), ec = __shfl_down(c4.x, 1), ep = __shfl_down(rp.x, 1);
    if (qz) { lm = 0.f; lc = 0.f; lp = 0.f; }
    if (qe) { em = 0.f; ec = 0.f; ep = 0.f; }

    // ---- 9-tap FMA per element ----
    float4 a = make_float4(0.f, 0.f, 0.f, 0.f);
    // dr = -1 (taps 0,1,2)
    a.x = fmaf(lm,   wv[0].x, a.x); a.y = fmaf(rm.x, wv[0].y, a.y);
    a.z = fmaf(rm.y, wv[0].z, a.z); a.w = fmaf(rm.z, wv[0].w, a.w);
    a.x = fmaf(rm.x, wv[1].x, a.x); a.y = fmaf(rm.y, wv[1].y, a.y);
    a.z = fmaf(rm.z, wv[1].z, a.z); a.w = fmaf(rm.w, wv[1].w, a.w);
    a.x = fmaf(rm.y, wv[2].x, a.x); a.y = fmaf(rm.z, wv[2].y, a.y);
    a.z = fmaf(rm.w, wv[2].z, a.z); a.w = fmaf(em,   wv[2].w, a.w);
    // dr = 0 (taps 3,4,5)
    a.x = fmaf(lc,   wv[3].x, a.x); a.y = fmaf(c4.x, wv[3].y, a.y);
    a.z = fmaf(c4.y, wv[3].z, a.z); a.w = fmaf(c4.z, wv[3].w, a.w);
    a.x = fmaf(c4.x, wv[4].x, a.x); a.y = fmaf(c4.y, wv[4].y, a.y);
    a.z = fmaf(c4.z, wv[4].z, a.z); a.w = fmaf(c4.w, wv[4].w, a.w);
    a.x = fmaf(c4.y, wv[5].x, a.x); a.y = fmaf(c4.z, wv[5].y, a.y);
    a.z = fmaf(c4.w, wv[5].z, a.z); a.w = fmaf(ec,   wv[5].w, a.w);
    // dr = +1 (taps 6,7,8)
    a.x = fmaf(lp,   wv[6].x, a.x); a.y = fmaf(rp.x, wv[6].y, a.y);
    a.z = fmaf(rp.y, wv[6].z, a.z); a.w = fmaf(rp.z, wv[6].w, a.w);
    a.x = fmaf(rp.x, wv[7].x, a.x); a.y = fmaf(rp.y, wv[7].y, a.y);
    a.z = fmaf(rp.z, wv[7].z, a.z); a.w = fmaf(rp.w, wv[7].w, a.w);
    a.x = fmaf(rp.y, wv[8].x, a.x); a.y = fmaf(rp.z, wv[8].y, a.y);
    a.z = fmaf(rp.w, wv[8].z, a.z); a.w = fmaf(ep,   wv[8].w, a.w);

    if (lane < 56u) {
        float* op = out + ((size_t)n * CC + c) * LL + l;
        *(float4*)op = a;
    }
}

extern "C" void kernel_launch(void* const* d_in, const int* in_sizes, int n_in,
                              void* d_out, int out_size, void* d_ws, size_t ws_size,
                              hipStream_t stream) {
    const float* in = (const float*)d_in[0];
    const float* wt = (const float*)d_in[1];
    float* out = (float*)d_out;
    agg_kernel<<<dim3(NWG), dim3(512), 0, stream>>>(in, wt, out);
}